// Round 1
// baseline (165.959 us; speedup 1.0000x reference)
//
#include <hip/hip_runtime.h>
#include <hip/hip_bf16.h>

#define B_N     2048
#define IN_N    512
#define SEQ_N   128
#define HID_N   12
#define HP_N    16   // padded hidden
#define OUT_N   3

__device__ __forceinline__ float fast_tanh(float x) {
    // tanh(x) = 1 - 2/(exp2(2*log2e*x)+1); safe at +/-inf
    float e = __builtin_amdgcn_exp2f(x * 2.8853900817779268f);
    return 1.0f - 2.0f * __builtin_amdgcn_rcpf(e + 1.0f);
}

// ---------------------------------------------------------------------------
// Kernel A: pre[b][s][h] = sum_i emb[x[b,i], s] * w_ih_f[h,i] + b_ih_f[h] + b_hh_f[h]
// One block per b. 128 threads: t = sg(0..31) + 32*ic(0..3).
// Thread owns s in [4*sg, 4*sg+3], i in [128*ic, 128*ic+127]. acc[4][12].
// ---------------------------------------------------------------------------
__global__ __launch_bounds__(128) void k_pre(
    const int* __restrict__ x, const float* __restrict__ emb,
    const float* __restrict__ w_ih_f,
    const float* __restrict__ b_ih_f, const float* __restrict__ b_hh_f,
    float* __restrict__ preF)
{
    __shared__ int xb[IN_N];
    __shared__ __align__(16) float smem[IN_N * 16];  // wT[i][16], later partials

    const int t = threadIdx.x;
    const int b = blockIdx.x;

    // stage x row (512 ints, int4 per thread)
    ((int4*)xb)[t] = ((const int4*)(x + b * IN_N))[t];

    // stage w_ih_f transposed: wT[i][h], pad h=12..15 with 0
    #pragma unroll
    for (int ii = 0; ii < 4; ++ii) {
        int i = t + ii * 128;
        float tmp[12];
        #pragma unroll
        for (int h = 0; h < 12; ++h) tmp[h] = w_ih_f[h * IN_N + i];
        float4* dst = (float4*)(smem + i * 16);
        dst[0] = make_float4(tmp[0], tmp[1], tmp[2], tmp[3]);
        dst[1] = make_float4(tmp[4], tmp[5], tmp[6], tmp[7]);
        dst[2] = make_float4(tmp[8], tmp[9], tmp[10], tmp[11]);
        dst[3] = make_float4(0.f, 0.f, 0.f, 0.f);
    }
    __syncthreads();

    const int sg = t & 31;   // s-quad index
    const int ic = t >> 5;   // i-chunk index

    float acc[4][12];
    #pragma unroll
    for (int c = 0; c < 4; ++c)
        #pragma unroll
        for (int h = 0; h < 12; ++h) acc[c][h] = 0.f;

    const float4* embq = (const float4*)emb;  // row = 32 float4
    const int i0 = ic * 128;

    for (int k = 0; k < 128; ++k) {
        int i = i0 + k;
        int r = xb[i];
        float4 e4 = embq[r * 32 + sg];        // emb[r, 4sg..4sg+3]
        const float4* wv = (const float4*)(smem + (i << 4));
        float4 w0 = wv[0], w1 = wv[1], w2 = wv[2];
        float ee[4] = {e4.x, e4.y, e4.z, e4.w};
        float ww[12] = {w0.x, w0.y, w0.z, w0.w,
                        w1.x, w1.y, w1.z, w1.w,
                        w2.x, w2.y, w2.z, w2.w};
        #pragma unroll
        for (int c = 0; c < 4; ++c)
            #pragma unroll
            for (int h = 0; h < 12; ++h)
                acc[c][h] += ee[c] * ww[h];
    }

    __syncthreads();  // done with wT; reuse smem for partials

    // write partials: smem[(s*4 + ic)*12 + h], s = sg*4+c
    #pragma unroll
    for (int c = 0; c < 4; ++c) {
        int s = sg * 4 + c;
        float4* dst = (float4*)(smem + (s * 4 + ic) * 12);
        dst[0] = make_float4(acc[c][0], acc[c][1], acc[c][2], acc[c][3]);
        dst[1] = make_float4(acc[c][4], acc[c][5], acc[c][6], acc[c][7]);
        dst[2] = make_float4(acc[c][8], acc[c][9], acc[c][10], acc[c][11]);
    }
    __syncthreads();

    // thread t reduces s = t across the 4 i-chunks, adds biases, stores padded row
    {
        int s = t;
        float o[12];
        #pragma unroll
        for (int h = 0; h < 12; ++h) o[h] = b_ih_f[h] + b_hh_f[h];
        #pragma unroll
        for (int icc = 0; icc < 4; ++icc) {
            const float* src = smem + (s * 4 + icc) * 12;
            #pragma unroll
            for (int h = 0; h < 12; ++h) o[h] += src[h];
        }
        float4* dst = (float4*)(preF + (((size_t)b << 7) + s) * HP_N);
        dst[0] = make_float4(o[0], o[1], o[2], o[3]);
        dst[1] = make_float4(o[4], o[5], o[6], o[7]);
        dst[2] = make_float4(o[8], o[9], o[10], o[11]);
        dst[3] = make_float4(0.f, 0.f, 0.f, 0.f);
    }
}

// ---------------------------------------------------------------------------
// Kernel B: rev[b][h] = tanh( sum_i emb[x[b,i],127] * w_ih_r[h,i] + b_ih_r[h] + b_hh_r[h] )
// One wave per b (4 b per 256-thread block). Lane l accumulates i = l + 64k.
// ---------------------------------------------------------------------------
__global__ __launch_bounds__(256) void k_rev(
    const int* __restrict__ x, const float* __restrict__ emb,
    const float* __restrict__ w_ih_r,
    const float* __restrict__ b_ih_r, const float* __restrict__ b_hh_r,
    float* __restrict__ rev)
{
    const int b = blockIdx.x * 4 + (threadIdx.x >> 6);
    const int l = threadIdx.x & 63;

    float p[12];
    #pragma unroll
    for (int h = 0; h < 12; ++h) p[h] = 0.f;

    for (int k = 0; k < 8; ++k) {
        int i = l + k * 64;
        int r = x[b * IN_N + i];
        float ev = emb[r * SEQ_N + 127];
        #pragma unroll
        for (int h = 0; h < 12; ++h) p[h] += ev * w_ih_r[h * IN_N + i];
    }
    // wave-wide butterfly reduction (64 lanes)
    #pragma unroll
    for (int off = 32; off; off >>= 1) {
        #pragma unroll
        for (int h = 0; h < 12; ++h) p[h] += __shfl_xor(p[h], off);
    }
    if (l == 0) {
        #pragma unroll
        for (int h = 0; h < 12; ++h)
            rev[b * HP_N + h] = fast_tanh(p[h] + b_ih_r[h] + b_hh_r[h]);
        #pragma unroll
        for (int h = 12; h < 16; ++h) rev[b * HP_N + h] = 0.f;
    }
}

// ---------------------------------------------------------------------------
// Kernel C: the serial scan. 64 threads = 1 wave = 4 batches; 16-lane group
// per b, lane j (<12) owns hidden unit j. h exchanged through intra-wave LDS.
// pre prefetched 8 steps deep to hide L2/HBM latency in the serial chain.
// ---------------------------------------------------------------------------
__global__ __launch_bounds__(64) void k_rnn(
    const float* __restrict__ preF, const float* __restrict__ rev,
    const float* __restrict__ w_hh_f,
    const float* __restrict__ fc_w, const float* __restrict__ fc_b,
    float* __restrict__ out)
{
    __shared__ __align__(16) float hx[4][20];      // 20-word group stride: pad
    __shared__ __align__(16) float ho[4][2][16];   // epilogue staging

    const int l = threadIdx.x;
    const int g = l >> 4;
    const int j = l & 15;
    const int b = blockIdx.x * 4 + g;
    const int jj = (j < 12) ? j : 0;

    // W_hh row for this lane (48B offset -> 16B aligned)
    const float4* wr = (const float4*)(w_hh_f + jj * 12);
    float4 w0 = wr[0], w1 = wr[1], w2 = wr[2];
    float W[12] = {w0.x, w0.y, w0.z, w0.w, w1.x, w1.y, w1.z, w1.w,
                   w2.x, w2.y, w2.z, w2.w};

    hx[g][j] = 0.f;  // h0 = 0 (slots 12..15 never read by the f4 loads)

    const float* pb = preF + ((size_t)b << 11);  // b*128*16

    float pq[8];
    #pragma unroll
    for (int k = 0; k < 8; ++k) pq[k] = pb[k * HP_N + j];

    float h = 0.f;
    for (int s8 = 0; s8 < 16; ++s8) {
        #pragma unroll
        for (int k = 0; k < 8; ++k) {
            int s = s8 * 8 + k;
            float p = pq[k];
            int sn = s + 8;
            if (sn < 128) pq[k] = pb[sn * HP_N + j];   // prefetch
            float4 a0 = *(const float4*)&hx[g][0];
            float4 a1 = *(const float4*)&hx[g][4];
            float4 a2 = *(const float4*)&hx[g][8];
            float acc = p
                + W[0] * a0.x + W[1] * a0.y + W[2]  * a0.z + W[3]  * a0.w
                + W[4] * a1.x + W[5] * a1.y + W[6]  * a1.z + W[7]  * a1.w
                + W[8] * a2.x + W[9] * a2.y + W[10] * a2.z + W[11] * a2.w;
            float nh = fast_tanh(acc);
            hx[g][j] = nh;   // same-wave DS ops are ordered; no barrier needed
            h = nh;
        }
    }

    // epilogue: out[b, o] = fc_b[o] + sum_k fc_w[o,k]*hf[k] + fc_w[o,12+k]*hr[k]
    ho[g][0][j] = h;
    ho[g][1][j] = rev[b * HP_N + j];   // pads were written as 0 by k_rev
    if (j < 3) {
        const float* fw = fc_w + j * 24;
        float o = fc_b[j];
        #pragma unroll
        for (int k = 0; k < 12; ++k)
            o += fw[k] * ho[g][0][k] + fw[12 + k] * ho[g][1][k];
        out[b * OUT_N + j] = o;
    }
}

// ---------------------------------------------------------------------------
extern "C" void kernel_launch(void* const* d_in, const int* in_sizes, int n_in,
                              void* d_out, int out_size, void* d_ws, size_t ws_size,
                              hipStream_t stream) {
    const int*   x      = (const int*)  d_in[0];
    const float* emb    = (const float*)d_in[1];
    const float* w_ih_f = (const float*)d_in[2];
    const float* w_hh_f = (const float*)d_in[3];
    const float* b_ih_f = (const float*)d_in[4];
    const float* b_hh_f = (const float*)d_in[5];
    const float* w_ih_r = (const float*)d_in[6];
    // d_in[7] = w_hh_r: unused by the reference output
    const float* b_ih_r = (const float*)d_in[8];
    const float* b_hh_r = (const float*)d_in[9];
    const float* fc_w   = (const float*)d_in[10];
    const float* fc_b   = (const float*)d_in[11];
    float* out = (float*)d_out;

    float* preF = (float*)d_ws;                       // 2048*128*16 f32 = 16 MB
    float* rev  = preF + (size_t)B_N * SEQ_N * HP_N;  // 2048*16 f32

    k_pre<<<B_N, 128, 0, stream>>>(x, emb, w_ih_f, b_ih_f, b_hh_f, preF);
    k_rev<<<B_N / 4, 256, 0, stream>>>(x, emb, w_ih_r, b_ih_r, b_hh_r, rev);
    k_rnn<<<B_N / 4, 64, 0, stream>>>(preF, rev, w_hh_f, fc_w, fc_b, out);
}

// Round 2
// 150.912 us; speedup vs baseline: 1.0997x; 1.0997x over previous
//
#include <hip/hip_runtime.h>
#include <hip/hip_bf16.h>

#define B_N     2048
#define IN_N    512
#define SEQ_N   128
#define HID_N   12
#define HP_N    16
#define OUT_N   3

typedef __attribute__((ext_vector_type(8))) short short8;
typedef __attribute__((ext_vector_type(4))) float f32x4;
typedef unsigned int uint;
typedef unsigned short ushort;

__device__ __forceinline__ float fast_tanh(float x) {
    float e = __builtin_amdgcn_exp2f(x * 2.8853900817779268f);
    return 1.0f - 2.0f * __builtin_amdgcn_rcpf(e + 1.0f);
}

__device__ __forceinline__ ushort f2bf(float f) {   // RNE fp32->bf16
    uint u = __float_as_uint(f);
    u += 0x7fffu + ((u >> 16) & 1u);
    return (ushort)(u >> 16);
}

__device__ __forceinline__ float bf2f(ushort s) {
    return __uint_as_float(((uint)s) << 16);
}

// ---------------------------------------------------------------------------
// Prep: emb (512x128 f32) -> embB bf16; wBT[16][512] = zero-padded w_ih_f.
// ---------------------------------------------------------------------------
__global__ __launch_bounds__(256) void k_prep(
    const float* __restrict__ emb, const float* __restrict__ w_ih_f,
    ushort* __restrict__ embB, ushort* __restrict__ wBT)
{
    int tid = blockIdx.x * 256 + threadIdx.x;      // 0..16383
    float4 e = ((const float4*)emb)[tid];
    uint2 o;
    o.x = (uint)f2bf(e.x) | ((uint)f2bf(e.y) << 16);
    o.y = (uint)f2bf(e.z) | ((uint)f2bf(e.w) << 16);
    ((uint2*)embB)[tid] = o;
    if (tid < 16 * IN_N)
        wBT[tid] = (tid < HID_N * IN_N) ? f2bf(w_ih_f[tid]) : (ushort)0;
}

// ---------------------------------------------------------------------------
// k_pre: per-b GEMM  preB[b][s][h] = sum_i embB[xb[i]][s] * wBT[h][i]
// via mfma_f32_16x16x32_bf16.  One block per b, 128 threads (2 waves).
// A staged transposed in LDS As[s][i_chunk] stride 136 (272B, 16B-aligned,
// 2-way banks). B-frags straight from global (16KB, cache-resident).
// ---------------------------------------------------------------------------
__global__ __launch_bounds__(128) void k_pre(
    const int* __restrict__ x, const ushort* __restrict__ embB,
    const ushort* __restrict__ wBT, ushort* __restrict__ preB)
{
    __shared__ int xb[IN_N];
    __shared__ __align__(16) ushort As[128 * 136];

    const int t = threadIdx.x;
    const int b = blockIdx.x;

    ((int4*)xb)[t] = ((const int4*)(x + b * IN_N))[t];
    __syncthreads();

    const int l      = t & 63;
    const int w      = t >> 6;        // wave 0/1
    const int lane16 = l & 15;
    const int quad   = l >> 4;        // 0..3
    const int q      = t & 31;        // row-quad for staging
    const int sq     = t >> 5;        // s-quarter for staging (32 s each)

    f32x4 acc[4] = {{0.f,0.f,0.f,0.f},{0.f,0.f,0.f,0.f},
                    {0.f,0.f,0.f,0.f},{0.f,0.f,0.f,0.f}};

    for (int c = 0; c < 4; ++c) {
        // gather this thread's 4 rows (64B of s-range each)
        union { uint4 v4[4]; uint v[16]; } R[4];
        const int ibase = c * 128 + q * 4;
        #pragma unroll
        for (int k = 0; k < 4; ++k) {
            const uint4* rp = (const uint4*)(embB + (size_t)xb[ibase + k] * SEQ_N + sq * 32);
            #pragma unroll
            for (int u = 0; u < 4; ++u) R[k].v4[u] = rp[u];
        }
        // B fragments for this chunk (global, L1-hit after first block)
        short8 bfr[4];
        #pragma unroll
        for (int ks = 0; ks < 4; ++ks)
            bfr[ks] = *(const short8*)(wBT + lane16 * IN_N + c * 128 + ks * 32 + quad * 8);

        if (c) __syncthreads();   // everyone done reading previous As

        // transpose-pack: As[s][4q..4q+3] <- rows' element s
        #pragma unroll
        for (int p = 0; p < 16; ++p) {
            uint r0 = R[0].v[p], r1 = R[1].v[p], r2 = R[2].v[p], r3 = R[3].v[p];
            int s0 = sq * 32 + p * 2;
            uint lo01 = (r0 & 0xffffu) | (r1 << 16);
            uint lo23 = (r2 & 0xffffu) | (r3 << 16);
            *(uint2*)&As[s0 * 136 + q * 4] = make_uint2(lo01, lo23);
            uint hi01 = (r0 >> 16) | (r1 & 0xffff0000u);
            uint hi23 = (r2 >> 16) | (r3 & 0xffff0000u);
            *(uint2*)&As[(s0 + 1) * 136 + q * 4] = make_uint2(hi01, hi23);
        }
        __syncthreads();

        // MFMA: 4 s-tiles per wave, 4 K-steps per chunk
        #pragma unroll
        for (int tt = 0; tt < 4; ++tt) {
            const int row = (w * 4 + tt) * 16 + lane16;
            #pragma unroll
            for (int ks = 0; ks < 4; ++ks) {
                short8 af = *(const short8*)&As[row * 136 + ks * 32 + quad * 8];
                acc[tt] = __builtin_amdgcn_mfma_f32_16x16x32_bf16(af, bfr[ks], acc[tt], 0, 0, 0);
            }
        }
    }

    // epilogue: D[m][n]: n = lane16 (=h), m = quad*4 + r (s within tile)
    if (lane16 < HID_N) {
        #pragma unroll
        for (int tt = 0; tt < 4; ++tt) {
            #pragma unroll
            for (int r = 0; r < 4; ++r) {
                int s = (w * 4 + tt) * 16 + quad * 4 + r;
                preB[((size_t)b * SEQ_N + s) * HP_N + lane16] = f2bf(acc[tt][r]);
            }
        }
    }
}

// ---------------------------------------------------------------------------
// k_rev: rev[b][h] = tanh( sum_i emb[x[b,i],127]*w_ih_r[h,i] + b_ih_r + b_hh_r )
// ---------------------------------------------------------------------------
__global__ __launch_bounds__(256) void k_rev(
    const int* __restrict__ x, const float* __restrict__ emb,
    const float* __restrict__ w_ih_r,
    const float* __restrict__ b_ih_r, const float* __restrict__ b_hh_r,
    float* __restrict__ rev)
{
    const int b = blockIdx.x * 4 + (threadIdx.x >> 6);
    const int l = threadIdx.x & 63;

    float p[12];
    #pragma unroll
    for (int h = 0; h < 12; ++h) p[h] = 0.f;

    for (int k = 0; k < 8; ++k) {
        int i = l + k * 64;
        int r = x[b * IN_N + i];
        float ev = emb[r * SEQ_N + 127];
        #pragma unroll
        for (int h = 0; h < 12; ++h) p[h] += ev * w_ih_r[h * IN_N + i];
    }
    #pragma unroll
    for (int off = 32; off; off >>= 1) {
        #pragma unroll
        for (int h = 0; h < 12; ++h) p[h] += __shfl_xor(p[h], off);
    }
    if (l == 0) {
        #pragma unroll
        for (int h = 0; h < 12; ++h)
            rev[b * HP_N + h] = fast_tanh(p[h] + b_ih_r[h] + b_hh_r[h]);
        #pragma unroll
        for (int h = 12; h < 16; ++h) rev[b * HP_N + h] = 0.f;
    }
}

// ---------------------------------------------------------------------------
// k_rnn: 16 lanes per b (lane j owns hidden j), h broadcast via ds_bpermute
// (no LDS round-trip). 256 thr = 16 b per block, 128 blocks.
// ---------------------------------------------------------------------------
__global__ __launch_bounds__(256) void k_rnn(
    const ushort* __restrict__ preB, const float* __restrict__ rev,
    const float* __restrict__ w_hh_f,
    const float* __restrict__ b_ih_f, const float* __restrict__ b_hh_f,
    const float* __restrict__ fc_w, const float* __restrict__ fc_b,
    float* __restrict__ out)
{
    __shared__ float ho[16][40];

    const int tid = threadIdx.x;
    const int l   = tid & 63;
    const int j   = l & 15;
    const int jj  = (j < 12) ? j : 0;
    const int gid = tid >> 4;                 // 0..15 in block
    const int b   = blockIdx.x * 16 + gid;
    const int baseaddr = (l & 48) << 2;       // group-base lane * 4

    const float4* wr = (const float4*)(w_hh_f + jj * 12);
    float4 w0 = wr[0], w1 = wr[1], w2 = wr[2];
    float W[12] = {w0.x, w0.y, w0.z, w0.w, w1.x, w1.y, w1.z, w1.w,
                   w2.x, w2.y, w2.z, w2.w};
    const float bias = b_ih_f[jj] + b_hh_f[jj];

    const ushort* pb = preB + (size_t)b * SEQ_N * HP_N + j;
    ushort pq[8];
    #pragma unroll
    for (int k = 0; k < 8; ++k) pq[k] = pb[k * HP_N];

    float h = 0.f;
    for (int s8 = 0; s8 < 16; ++s8) {
        #pragma unroll
        for (int k = 0; k < 8; ++k) {
            int s = s8 * 8 + k;
            float p = bf2f(pq[k]) + bias;
            pq[k] = pb[((s + 8) & 127) * HP_N];     // branchless prefetch
            int hb = __float_as_int(h);
            float hk[12];
            #pragma unroll
            for (int kk = 0; kk < 12; ++kk)
                hk[kk] = __int_as_float(__builtin_amdgcn_ds_bpermute(baseaddr + 4 * kk, hb));
            float c0 = p, c1 = 0.f, c2 = 0.f;
            #pragma unroll
            for (int u = 0; u < 4; ++u) {
                c0 = __builtin_fmaf(W[u],     hk[u],     c0);
                c1 = __builtin_fmaf(W[4 + u], hk[4 + u], c1);
                c2 = __builtin_fmaf(W[8 + u], hk[8 + u], c2);
            }
            h = fast_tanh(c0 + c1 + c2);
        }
    }

    // epilogue FC (intra-wave LDS, no barrier needed)
    ho[gid][j]      = h;
    ho[gid][20 + j] = rev[b * HP_N + j];
    if (j < OUT_N) {
        const float* fw = fc_w + j * 24;
        float o = fc_b[j];
        #pragma unroll
        for (int k = 0; k < 12; ++k)
            o += fw[k] * ho[gid][k] + fw[12 + k] * ho[gid][20 + k];
        out[b * OUT_N + j] = o;
    }
}

// ---------------------------------------------------------------------------
extern "C" void kernel_launch(void* const* d_in, const int* in_sizes, int n_in,
                              void* d_out, int out_size, void* d_ws, size_t ws_size,
                              hipStream_t stream) {
    const int*   x      = (const int*)  d_in[0];
    const float* emb    = (const float*)d_in[1];
    const float* w_ih_f = (const float*)d_in[2];
    const float* w_hh_f = (const float*)d_in[3];
    const float* b_ih_f = (const float*)d_in[4];
    const float* b_hh_f = (const float*)d_in[5];
    const float* w_ih_r = (const float*)d_in[6];
    const float* b_ih_r = (const float*)d_in[8];
    const float* b_hh_r = (const float*)d_in[9];
    const float* fc_w   = (const float*)d_in[10];
    const float* fc_b   = (const float*)d_in[11];
    float* out = (float*)d_out;

    ushort* preB = (ushort*)d_ws;                              // 8 MB
    float*  rev  = (float*)((char*)d_ws + 8388608);            // 128 KB
    ushort* embB = (ushort*)((char*)d_ws + 8519680);           // 128 KB
    ushort* wBT  = (ushort*)((char*)d_ws + 8650752);           // 16 KB

    k_prep<<<64,   256, 0, stream>>>(emb, w_ih_f, embB, wBT);
    k_pre <<<B_N,  128, 0, stream>>>(x, embB, wBT, preB);
    k_rev <<<B_N/4,256, 0, stream>>>(x, emb, w_ih_r, b_ih_r, b_hh_r, rev);
    k_rnn <<<B_N/16,256,0, stream>>>(preB, rev, w_hh_f, b_ih_f, b_hh_f, fc_w, fc_b, out);
}